// Round 7
// baseline (204.149 us; speedup 1.0000x reference)
//
#include <hip/hip_runtime.h>
#include <hip/hip_bf16.h>

using bf16 = __hip_bfloat16;
using bf16x8 = __attribute__((ext_vector_type(8))) short;  // 8 bf16 (4 VGPRs)
using f32x4  = __attribute__((ext_vector_type(4))) float;

#define NN 512
#define NS 511

// ---------------- workspace layout (float offsets) ----------------
// XS1 holds 513 rows: row 512 is an all-zero feature row used by the
// invalid edge slot (idx==511 -> i==512), replacing per-slot predication.
enum : int {
  WS_XS1  = 256,      // [513][64][4] (x0,x1x,x1y,x1z) — 16B aligned
  WS_POS2 = 131584,   // [512][3] positions after layer-0 update
  WS_DELTA= 133120,   // [512][3] layer-0 displacement
};                     // end = 134656 floats ~= 539 KB

// exact RNE float->bf16 bits (no NaN inputs here)
__device__ __forceinline__ short f2b(float x) {
  unsigned u = __builtin_bit_cast(unsigned, x);
  unsigned r = (u + 0x7fffu + ((u >> 16) & 1u)) >> 16;
  return (short)r;
}

// dtype-branched scalar load (branch, NOT select: f32-view OOB if input is bf16)
__device__ __forceinline__ float ld(const void* p, int i, int isf32) {
  if (isf32) return ((const float*)p)[i];
  return __bfloat162float(((const bf16*)p)[i]);
}

// Shared block for the edgenode body (sized for L=1; L=0 uses a prefix of Bhi)
// gt: per-edge-slot geometry (Y1[3], Y2[5], r, pad) computed once at staging.
// X0l has a 6th all-zero row (species index 5) for the invalid slot; spl[512]
// maps the invalid slot to it.
struct SB {
  short Bhi[320 * 40];   // [n][h], row stride 40 shorts (80B, 16B-aligned)
  float red[4][64][9];
  float Af[64][9];
  float s0l[64];
  float o1l[3][64];
  float hl[64];
  float X0l[384];        // L0: species-indexed x0 table (rows 0-4 real, 5 zero)
  float gt[NN][10];      // per-edge-slot geometry table (j-specific)
  int   spl[NN + 4];     // L0: species per node; spl[512]=5 (zero row)
  int   flag;
};

// ---------------- fused edge + aggregate + node update --------------
// 59.4 us/dispatch verified loop (128 VGPR, 2 waves/SIMD). VGPR>128 is a
// cliff (rounds 1-2: +8 VGPR => 1 wave/SIMD, +20-30%/dispatch). ROUND 7:
// predication removed from the accumulate block — invalid slot idx==511 now
// reads an exact-zero feature row (s0=s1=0 => contribution 0.0), so vld[],
// the i>511 clamp, and 16 predicated regions per stile disappear. Strictly
// register-reducing.
template <int L>
__device__ __forceinline__ void edge_body(
    int j, int t, SB& s, const void* __restrict__ positions,
    const int* __restrict__ nodef, const void* __restrict__ te,
    const void* __restrict__ W_embed, const void* __restrict__ b_embed,
    const void* __restrict__ W_lin,
    const void* __restrict__ W_e1, const void* __restrict__ b_e1,
    const void* __restrict__ W_e2, const void* __restrict__ Wp0,
    const void* __restrict__ Wp1, const void* __restrict__ Wr1,
    const void* __restrict__ br1, const void* __restrict__ Wr2g,
    float* __restrict__ ws, void* __restrict__ out) {
  constexpr int HAS1 = L;          // s1==0 in layer 0
  constexpr int K = HAS1 ? 5 : 3;  // s2==0 always
  constexpr int N = K * 64;
  const int lane = t & 63;
  const int wave = t >> 6;          // 0..3
  const int quad = lane >> 4;
  const int lo = lane & 15;

  // ---- dtype sniff (per block) ----
  if (t < 64) {
    int cnt = 0;
    #pragma unroll
    for (int kq = 0; kq < 4; ++kq) {
      float v = __bfloat162float(((const bf16*)W_embed)[t + kq * 64]);
      float av = fabsf(v);
      cnt += (v == v && av > 1e-8f && av < 1e4f) ? 1 : 0;
    }
    #pragma unroll
    for (int off = 32; off > 0; off >>= 1) cnt += __shfl_down(cnt, off);
    if (t == 0) s.flag = (cnt >= 240) ? 0 : 1;
  }
  __syncthreads();
  const int isf32 = s.flag;

  const float* pos2 = ws + WS_POS2;  // L1 position source (written by L0)

  const float s3 = 1.7320508075688772f;
  const float s5h = 1.118033988749895f;    // 0.5*sqrt(5)
  const float s15 = 3.872983346207417f;
  const float s15h = 1.9364916731037085f;  // 0.5*sqrt(15)

  float pjx, pjy, pjz;
  if (HAS1) {
    pjx = pos2[j * 3 + 0]; pjy = pos2[j * 3 + 1]; pjz = pos2[j * 3 + 2];
  } else {
    pjx = ld(positions, j * 3 + 0, isf32);
    pjy = ld(positions, j * 3 + 1, isf32);
    pjz = ld(positions, j * 3 + 2, isf32);
  }

  {  // stage W2 slice -> LDS bf16 (direct bit copy if input already bf16)
    for (int idx = t; idx < N * 32; idx += 256) {
      int n = idx >> 5, h = idx & 31;
      int kp = n >> 6, f = n & 63;
      int src = (L * 32 + h) * 384 + f * 6 + kp;
      short bits;
      if (isf32) bits = f2b(((const float*)W_e2)[src]);
      else       bits = ((const short*)W_e2)[src];
      s.Bhi[n * 40 + h] = bits;
    }
    // geometry table: gt[ida] = {Y1(3), Y2(5), r} for edge slot ida -> j
    for (int ida = t; ida < NN; ida += 256) {
      int ia = ida + (ida >= j);
      if (ia > 511) ia = 511;  // pos-read clamp only; slot zeroed via features
      float qx, qy, qz;
      if (HAS1) {
        qx = pos2[ia * 3 + 0]; qy = pos2[ia * 3 + 1]; qz = pos2[ia * 3 + 2];
      } else {
        qx = ld(positions, ia * 3 + 0, isf32);
        qy = ld(positions, ia * 3 + 1, isf32);
        qz = ld(positions, ia * 3 + 2, isf32);
      }
      float vx = pjx - qx, vy = pjy - qy, vz = pjz - qz;
      float r2 = vx * vx + vy * vy + vz * vz;
      float r = sqrtf(r2);
      float rinv = r2 > 0.f ? rsqrtf(r2) : 0.f;
      float ux = vx * rinv, uy = vy * rinv, uz = vz * rinv;
      float* g = &s.gt[ida][0];
      g[0] = s3 * ux; g[1] = s3 * uy; g[2] = s3 * uz;
      g[3] = s15 * ux * uy;
      g[4] = s15 * uy * uz;
      g[5] = s5h * (3.f * uz * uz - 1.f);
      g[6] = s15 * ux * uz;
      g[7] = s15h * (ux * ux - uy * uy);
      g[8] = r;
    }
    if (!HAS1) {  // species table + in-block X0S (same math/order as k_pre)
      for (int idx = t; idx < NN; idx += 256) s.spl[idx] = nodef[idx] - 1;
      if (t == 0) s.spl[NN] = 5;  // invalid slot -> zero X0l row
      float* scr = &s.red[0][0][0];  // 2304 floats, dead until post-loop
      {  // te @ W_embed partials (4 k-chunks of 8)
        int q = t & 63, kc = t >> 6;
        float ptv = 0.f;
        #pragma unroll
        for (int k = kc * 8; k < kc * 8 + 8; ++k)
          ptv += ld(te, k, isf32) * ld(W_embed, (5 + k) * 64 + q, isf32);
        scr[kc * 64 + q] = ptv;
      }
      __syncthreads();
      if (t < 64)
        scr[256 + t] = scr[t] + scr[64 + t] + scr[128 + t] + scr[192 + t] +
                       ld(b_embed, t, isf32);
      __syncthreads();
      for (int idx = t; idx < 320; idx += 256) {
        int sp = idx >> 6, q = idx & 63;
        scr[512 + idx] = ld(W_embed, sp * 64 + q, isf32) + scr[256 + q];
      }
      __syncthreads();
      for (int idx = t; idx < 384; idx += 256) {
        float x = 0.f;
        if (idx < 320) {
          int sp = idx >> 6, f = idx & 63;
          #pragma unroll 8
          for (int q = 0; q < 64; ++q)
            x += scr[512 + sp * 64 + q] * ld(W_lin, q * 64 + f, isf32);
        }
        s.X0l[idx] = x;  // rows 320..383 = zero row (species 5)
      }
    }
  }
  const f32x4* xs = (const f32x4*)(ws + WS_XS1);  // used only for L==1
  float we1v[8], be1v[8];
  #pragma unroll
  for (int i = 0; i < 8; ++i) {
    we1v[i] = ld(W_e1, L * 32 + quad * 8 + i, isf32);
    be1v[i] = ld(b_e1, L * 32 + quad * 8 + i, isf32);
  }

  float acc[9][4] = {};  // [c][ft]
  __syncthreads();

  #pragma unroll 1
  for (int stile = wave; stile < 32; stile += 4) {
    // ---- A fragment: he for sender m=lo, k=quad*8+i (r from gt) ----
    bf16x8 af;
    {
      float r = s.gt[stile * 16 + lo][8];
      #pragma unroll
      for (int i = 0; i < 8; ++i) {
        float x = r * we1v[i] + be1v[i];
        float he = x / (1.f + __expf(-x));
        af[i] = f2b(he);
      }
    }
    // ---- Y + indices (+ species for L0): all from LDS, no predication ----
    float Y1r[4][3], Y2r[4][5];
    int ir[4], sp4[4];
    #pragma unroll
    for (int r4 = 0; r4 < 4; ++r4) {
      int idx = stile * 16 + quad * 4 + r4;
      int i = idx + (idx >= j);       // 0..512; slot 511 -> zero row 512
      ir[r4] = i;
      if (!HAS1) sp4[r4] = s.spl[i];  // spl[512]=5 -> zero X0l row
      const float* g = &s.gt[idx][0];  // broadcast within each quad
      Y1r[r4][0] = g[0]; Y1r[r4][1] = g[1]; Y1r[r4][2] = g[2];
      Y2r[r4][0] = g[3]; Y2r[r4][1] = g[4]; Y2r[r4][2] = g[5];
      Y2r[r4][3] = g[6]; Y2r[r4][4] = g[7];
    }
    // ---- per f-subtile: loads, K MFMAs, then message math ----
    #pragma unroll
    for (int ft = 0; ft < 4; ++ft) {
      int fcol = ft * 16 + lo;
      f32x4 xv[4];
      if (HAS1) {
        #pragma unroll
        for (int r4 = 0; r4 < 4; ++r4) xv[r4] = xs[ir[r4] * 64 + fcol];
      } else {
        #pragma unroll
        for (int r4 = 0; r4 < 4; ++r4) {
          f32x4 v = {s.X0l[sp4[r4] * 64 + fcol], 0.f, 0.f, 0.f};
          xv[r4] = v;
        }
      }
      f32x4 C[K];
      #pragma unroll
      for (int kp = 0; kp < K; ++kp) {
        const bf16x8 bh = *(const bf16x8*)&s.Bhi[(kp * 64 + fcol) * 40 + quad * 8];
        f32x4 c = {0.f, 0.f, 0.f, 0.f};
        C[kp] = __builtin_amdgcn_mfma_f32_16x16x32_bf16(af, bh, c, 0, 0, 0);
      }
      #pragma unroll
      for (int r4 = 0; r4 < 4; ++r4) {
        float s0 = xv[r4].x;
        float w0 = C[0][r4], w1 = C[1][r4], w2 = C[2][r4];
        if (HAS1) {
          float s1x = xv[r4].y, s1y = xv[r4].z, s1z = xv[r4].w;
          float w3 = C[3][r4], w4 = C[4][r4];
          float d1 = s1x * Y1r[r4][0] + s1y * Y1r[r4][1] + s1z * Y1r[r4][2];
          float cx = s1y * Y1r[r4][2] - s1z * Y1r[r4][1];
          float cy = s1z * Y1r[r4][0] - s1x * Y1r[r4][2];
          float cz = s1x * Y1r[r4][1] - s1y * Y1r[r4][0];
          acc[0][ft] += w0 * s0 + w3 * d1;
          float t1 = w1 * s0;
          acc[1][ft] += t1 * Y1r[r4][0] + w4 * cx;
          acc[2][ft] += t1 * Y1r[r4][1] + w4 * cy;
          acc[3][ft] += t1 * Y1r[r4][2] + w4 * cz;
        } else {
          acc[0][ft] += w0 * s0;
          float t1 = w1 * s0;
          acc[1][ft] += t1 * Y1r[r4][0];
          acc[2][ft] += t1 * Y1r[r4][1];
          acc[3][ft] += t1 * Y1r[r4][2];
        }
        float t2 = w2 * s0;
        acc[4][ft] += t2 * Y2r[r4][0];
        acc[5][ft] += t2 * Y2r[r4][1];
        acc[6][ft] += t2 * Y2r[r4][2];
        acc[7][ft] += t2 * Y2r[r4][3];
        acc[8][ft] += t2 * Y2r[r4][4];
      }
    }
  }

  // ---- reduce over quads (butterfly), then over 4 waves (LDS) -> Af ----
  #pragma unroll
  for (int c = 0; c < 9; ++c)
    #pragma unroll
    for (int ft = 0; ft < 4; ++ft) {
      float v = acc[c][ft];
      v += __shfl_xor(v, 16);
      v += __shfl_xor(v, 32);
      acc[c][ft] = v;
    }
  if (quad == 0) {
    #pragma unroll
    for (int c = 0; c < 9; ++c)
      #pragma unroll
      for (int ft = 0; ft < 4; ++ft)
        s.red[wave][ft * 16 + lo][c] = acc[c][ft];
  }
  __syncthreads();
  for (int o = t; o < 576; o += 256) {
    int f = o / 9, c = o % 9;
    s.Af[f][c] = (s.red[0][f][c] + s.red[1][f][c] + s.red[2][f][c] +
                  s.red[3][f][c]) * (1.f / 511.f);
  }
  __syncthreads();

  // ---- node-update tail (wave 0; other waves ride the barriers) ----
  float out0 = 0.f, o1x = 0.f, o1y = 0.f, o1z = 0.f;
  if (t < 64) {
    int f = t;
    float a[9];
    #pragma unroll
    for (int c = 0; c < 9; ++c) a[c] = s.Af[f][c];
    int sp = nodef[j] - 1;
    int b0i = ((L * 5 + sp) * 64 + f) * 6;
    int b1i = ((L * 5 + sp) * 64 + f) * 3;
    float A0 = a[0];
    float n1 = a[1] * a[1] + a[2] * a[2] + a[3] * a[3];
    float n2 = a[4] * a[4] + a[5] * a[5] + a[6] * a[6] + a[7] * a[7] + a[8] * a[8];
    float A02 = A0 * A0;
    out0 = ld(Wp0, b0i + 0, isf32) * A0 + ld(Wp0, b0i + 1, isf32) * A02 +
           ld(Wp0, b0i + 2, isf32) * A02 * A0 + ld(Wp0, b0i + 3, isf32) * n1 +
           ld(Wp0, b0i + 4, isf32) * n2 + ld(Wp0, b0i + 5, isf32) * A0 * n1;
    float gp = ld(Wp1, b1i + 0, isf32) + ld(Wp1, b1i + 1, isf32) * A0 +
               ld(Wp1, b1i + 2, isf32) * A02;
    o1x = gp * a[1]; o1y = gp * a[2]; o1z = gp * a[3];
    s.s0l[f] = out0;
    if (L == 0) { s.o1l[0][f] = o1x; s.o1l[1][f] = o1y; s.o1l[2][f] = o1z; }
  }
  __syncthreads();
  if (t < 64) {
    int f = t;
    if (L == 0) {
      // next-layer node linear into XS1 (read in the next dispatch)
      float b0 = 0.f, bx = 0.f, by = 0.f, bz = 0.f;
      #pragma unroll 8
      for (int q = 0; q < 64; ++q) {
        float w0 = ld(W_lin, 3 * 4096 + q * 64 + f, isf32);  // layer1, path0
        float w1 = ld(W_lin, 4 * 4096 + q * 64 + f, isf32);  // layer1, path1
        b0 += s.s0l[q] * w0;
        bx += s.o1l[0][q] * w1; by += s.o1l[1][q] * w1; bz += s.o1l[2][q] * w1;
      }
      f32x4 o = {b0, bx, by, bz};
      *(f32x4*)&ws[WS_XS1 + (j * 64 + f) * 4] = o;
      if (j == 0) {  // zero feature row 512 for the invalid edge slot
        f32x4 z = {0.f, 0.f, 0.f, 0.f};
        *(f32x4*)&ws[WS_XS1 + (512 * 64 + f) * 4] = z;
      }
    }
    float hacc = ld(br1, L * 64 + f, isf32);
    #pragma unroll 8
    for (int q = 0; q < 64; ++q)
      hacc += s.s0l[q] * ld(Wr1, (L * 64 + q) * 64 + f, isf32);
    s.hl[f] = hacc / (1.f + __expf(-hacc));
  }
  __syncthreads();
  if (t < 64) {
    int f = t;
    float gacc = 0.f;
    #pragma unroll 8
    for (int m = 0; m < 64; ++m)
      gacc += s.hl[m] * ld(Wr2g, (L * 64 + m) * 64 + f, isf32);
    float px = gacc * o1x, py = gacc * o1y, pz = gacc * o1z;
    #pragma unroll
    for (int off = 32; off > 0; off >>= 1) {
      px += __shfl_down(px, off);
      py += __shfl_down(py, off);
      pz += __shfl_down(pz, off);
    }
    if (f == 0) {
      if (L == 0) {
        ws[WS_DELTA + j * 3 + 0] = px;
        ws[WS_DELTA + j * 3 + 1] = py;
        ws[WS_DELTA + j * 3 + 2] = pz;
        ws[WS_POS2 + j * 3 + 0] = ld(positions, j * 3 + 0, isf32) + px;
        ws[WS_POS2 + j * 3 + 1] = ld(positions, j * 3 + 1, isf32) + py;
        ws[WS_POS2 + j * 3 + 2] = ld(positions, j * 3 + 2, isf32) + pz;
      } else {
        float ox = ws[WS_DELTA + j * 3 + 0] + px;
        float oy = ws[WS_DELTA + j * 3 + 1] + py;
        float oz = ws[WS_DELTA + j * 3 + 2] + pz;
        if (isf32) {
          float* o = (float*)out;
          o[j * 3 + 0] = ox; o[j * 3 + 1] = oy; o[j * 3 + 2] = oz;
        } else {
          bf16* o = (bf16*)out;
          o[j * 3 + 0] = __float2bfloat16(ox);
          o[j * 3 + 1] = __float2bfloat16(oy);
          o[j * 3 + 2] = __float2bfloat16(oz);
        }
      }
    }
  }
}

// ---------------- the two dispatched kernels ----------------
template <int L>
__global__ __launch_bounds__(256) void k_edgenode(
    const void* __restrict__ positions, const int* __restrict__ nodef,
    const void* __restrict__ te, const void* __restrict__ W_embed,
    const void* __restrict__ b_embed, const void* __restrict__ W_lin,
    const void* __restrict__ W_e1, const void* __restrict__ b_e1,
    const void* __restrict__ W_e2, const void* __restrict__ Wp0,
    const void* __restrict__ Wp1, const void* __restrict__ Wr1,
    const void* __restrict__ br1, const void* __restrict__ Wr2g,
    float* __restrict__ ws, void* __restrict__ out) {
  __shared__ SB s;
  edge_body<L>(blockIdx.x, threadIdx.x, s, positions, nodef, te, W_embed,
               b_embed, W_lin, W_e1, b_e1, W_e2, Wp0, Wp1, Wr1, br1, Wr2g,
               ws, out);
}

extern "C" void kernel_launch(void* const* d_in, const int* in_sizes, int n_in,
                              void* d_out, int out_size, void* d_ws, size_t ws_size,
                              hipStream_t stream) {
  const void* positions = d_in[0];
  const int*  nodef     = (const int*)d_in[1];
  const void* te        = d_in[2];
  const void* W_embed   = d_in[5];
  const void* b_embed   = d_in[6];
  const void* W_lin     = d_in[7];
  const void* W_e1      = d_in[8];
  const void* b_e1      = d_in[9];
  const void* W_e2      = d_in[10];
  const void* Wp0       = d_in[11];
  const void* Wp1       = d_in[12];
  const void* Wr1       = d_in[13];
  const void* br1       = d_in[14];
  const void* Wr2g      = d_in[16];
  float* ws = (float*)d_ws;
  (void)in_sizes; (void)n_in; (void)out_size; (void)ws_size;

  k_edgenode<0><<<dim3(512), dim3(256), 0, stream>>>(
      positions, nodef, te, W_embed, b_embed, W_lin, W_e1, b_e1, W_e2, Wp0,
      Wp1, Wr1, br1, Wr2g, ws, d_out);
  k_edgenode<1><<<dim3(512), dim3(256), 0, stream>>>(
      positions, nodef, te, W_embed, b_embed, W_lin, W_e1, b_e1, W_e2, Wp0,
      Wp1, Wr1, br1, Wr2g, ws, d_out);
}

// Round 8
// 180.588 us; speedup vs baseline: 1.1305x; 1.1305x over previous
//
#include <hip/hip_runtime.h>
#include <hip/hip_bf16.h>
#include <hip/hip_cooperative_groups.h>

namespace cg = cooperative_groups;

using bf16 = __hip_bfloat16;
using bf16x8 = __attribute__((ext_vector_type(8))) short;  // 8 bf16 (4 VGPRs)
using f32x4  = __attribute__((ext_vector_type(4))) float;

#define NN 512
#define NS 511

// ---------------- workspace layout (float offsets) ----------------
enum : int {
  WS_FLAG = 0,        // int: 0 = bf16 inputs, 1 = f32 inputs
  WS_X0S  = 16,       // [5][64] species-indexed layer-0 x0 rows (only 5 distinct!)
  WS_POS  = 336,      // [512][3] positions fp32 (layer 0)
  WS_POS2 = 1872,     // [512][3] positions after layer-0 update (layer 1 reads)
  WS_DELTA= 3408,     // [512][3] layer-0 displacement
  WS_XS1  = 4960,     // [512][64][4] (x0,x1x,x1y,x1z) for layer 1 — 16B aligned
};                     // end = 136032 floats ~= 544 KB

// exact RNE float->bf16 bits (no NaN inputs here)
__device__ __forceinline__ short f2b(float x) {
  unsigned u = __builtin_bit_cast(unsigned, x);
  unsigned r = (u + 0x7fffu + ((u >> 16) & 1u)) >> 16;
  return (short)r;
}

// dtype-branched scalar load (branch, NOT select: f32-view OOB if input is bf16)
__device__ __forceinline__ float ld(const void* p, int i, int isf32) {
  if (isf32) return ((const float*)p)[i];
  return __bfloat162float(((const bf16*)p)[i]);
}

// Shared block for the edgenode body (sized for L=1; L=0 uses a prefix of Bhi)
// gt: per-edge-slot geometry (Y1[3], Y2[5], r, pad) computed once at staging —
// removes all in-loop pos loads + Y/sqrt recompute from the 8x-replicated
// stile loop. Row stride 10 floats: lane-strided reads hit 16 distinct banks.
struct SB {
  short Bhi[320 * 40];   // [n][h], row stride 40 shorts (80B, 16B-aligned)
  float red[4][64][9];
  float Af[64][9];
  float s0l[64];
  float o1l[3][64];
  float hl[64];
  float X0l[320];        // L0: species-indexed x0 table
  float gt[NN][10];      // per-edge-slot geometry table (j-specific)
  int   spl[NN];         // L0: species per node
  int   flag;
};

// ---------------- pre body (dtype sniff + pos convert + X0S) ----------------
// b<5: X0S[b]; b==5: flag + pos convert. scr: >=576 floats of scratch.
__device__ __forceinline__ void pre_body(
    int b, int t, float* scr, int* flagp,
    const void* positions, const void* te, const void* W_embed,
    const void* b_embed, const void* W_lin, float* ws) {
  float* tvp = scr;          // [4][64]
  float* hst = scr + 256;    // [64]
  float* xp  = scr + 320;    // [4][64]
  if (t < 64) {
    int cnt = 0;
    #pragma unroll
    for (int kq = 0; kq < 4; ++kq) {
      float v = __bfloat162float(((const bf16*)W_embed)[t + kq * 64]);
      float av = fabsf(v);
      cnt += (v == v && av > 1e-8f && av < 1e4f) ? 1 : 0;
    }
    #pragma unroll
    for (int off = 32; off > 0; off >>= 1) cnt += __shfl_down(cnt, off);
    if (t == 0) *flagp = (cnt >= 240) ? 0 : 1;
  }
  __syncthreads();
  const int isf32 = *flagp;

  if (b == 5) {
    if (t == 0) ((int*)ws)[WS_FLAG] = isf32;
    for (int idx = t; idx < NN * 3; idx += 256)
      ws[WS_POS + idx] = ld(positions, idx, isf32);
  } else {
    {
      int q = t & 63, kc = t >> 6;  // 4 k-chunks of 8
      float ptv = 0.f;
      #pragma unroll
      for (int k = kc * 8; k < kc * 8 + 8; ++k)
        ptv += ld(te, k, isf32) * ld(W_embed, (5 + k) * 64 + q, isf32);
      tvp[kc * 64 + q] = ptv;
    }
    __syncthreads();
    if (t < 64)
      hst[t] = tvp[t] + tvp[64 + t] + tvp[128 + t] + tvp[192 + t] +
               ld(b_embed, t, isf32) + ld(W_embed, b * 64 + t, isf32);
    __syncthreads();
    {
      int f = t & 63, qc = t >> 6;  // 4 q-chunks of 16
      float px = 0.f;
      #pragma unroll
      for (int q2 = qc * 16; q2 < qc * 16 + 16; ++q2)
        px += hst[q2] * ld(W_lin, q2 * 64 + f, isf32);  // layer0 path0
      xp[qc * 64 + f] = px;
    }
    __syncthreads();
    if (t < 64)
      ws[WS_X0S + b * 64 + t] = xp[t] + xp[64 + t] + xp[128 + t] + xp[192 + t];
  }
}

// ---------------- fused edge + aggregate + node update --------------
// Stile loop register budget is a cliff (VGPR>128 => 1 wave/SIMD, +20-30%).
// Geometry hoisted to LDS gt[] at staging (same FLOPs, run once instead of
// 8x), removing 15 pos loads + sqrt/rsqrt + ~110 Y-ops per stile AND the
// pos/geometry register temporaries. L0 loop has zero global loads; L1 keeps
// only the xs stream. This exact module measured 59.3-59.8 us/dispatch,
// VGPR 128, dur_us 179.2 (round 5) — best of session. Rounds 1/2/7 each
// tried to edit this loop and tripped the 128->136 VGPR cliff (+35%).
template <int L>
__device__ __forceinline__ void edge_body(
    int j, int t, SB& s,
    const int* __restrict__ nodef, const void* __restrict__ W_lin,
    const void* __restrict__ W_e1, const void* __restrict__ b_e1,
    const void* __restrict__ W_e2, const void* __restrict__ Wp0,
    const void* __restrict__ Wp1, const void* __restrict__ Wr1,
    const void* __restrict__ br1, const void* __restrict__ Wr2g,
    float* __restrict__ ws, void* __restrict__ out) {
  constexpr int HAS1 = L;          // s1==0 in layer 0
  constexpr int K = HAS1 ? 5 : 3;  // s2==0 always
  constexpr int N = K * 64;
  const int lane = t & 63;
  const int wave = t >> 6;          // 0..3
  const int quad = lane >> 4;
  const int lo = lane & 15;

  const int isf32 = ((const int*)ws)[WS_FLAG];
  const float* pos = ws + (L ? WS_POS2 : WS_POS);

  const float s3 = 1.7320508075688772f;
  const float s5h = 1.118033988749895f;    // 0.5*sqrt(5)
  const float s15 = 3.872983346207417f;
  const float s15h = 1.9364916731037085f;  // 0.5*sqrt(15)

  const float pjx = pos[j * 3 + 0], pjy = pos[j * 3 + 1], pjz = pos[j * 3 + 2];

  {  // stage W2 slice -> LDS bf16 (direct bit copy if input already bf16)
    for (int idx = t; idx < N * 32; idx += 256) {
      int n = idx >> 5, h = idx & 31;
      int kp = n >> 6, f = n & 63;
      int src = (L * 32 + h) * 384 + f * 6 + kp;
      short bits;
      if (isf32) bits = f2b(((const float*)W_e2)[src]);
      else       bits = ((const short*)W_e2)[src];
      s.Bhi[n * 40 + h] = bits;
    }
    if (!HAS1) {
      for (int idx = t; idx < 320; idx += 256) s.X0l[idx] = ws[WS_X0S + idx];
      for (int idx = t; idx < NN; idx += 256) s.spl[idx] = nodef[idx] - 1;
    }
    // geometry table: gt[ida] = {Y1(3), Y2(5), r} for edge slot ida -> j
    for (int ida = t; ida < NN; ida += 256) {
      int ia = ida + (ida >= j);
      if (ia > 511) ia = 511;
      float vx = pjx - pos[ia * 3 + 0];
      float vy = pjy - pos[ia * 3 + 1];
      float vz = pjz - pos[ia * 3 + 2];
      float r2 = vx * vx + vy * vy + vz * vz;
      float r = sqrtf(r2);
      float rinv = r2 > 0.f ? rsqrtf(r2) : 0.f;
      float ux = vx * rinv, uy = vy * rinv, uz = vz * rinv;
      float* g = &s.gt[ida][0];
      g[0] = s3 * ux; g[1] = s3 * uy; g[2] = s3 * uz;
      g[3] = s15 * ux * uy;
      g[4] = s15 * uy * uz;
      g[5] = s5h * (3.f * uz * uz - 1.f);
      g[6] = s15 * ux * uz;
      g[7] = s15h * (ux * ux - uy * uy);
      g[8] = r;
    }
  }
  const f32x4* xs = (const f32x4*)(ws + WS_XS1);  // used only for L==1
  float we1v[8], be1v[8];
  #pragma unroll
  for (int i = 0; i < 8; ++i) {
    we1v[i] = ld(W_e1, L * 32 + quad * 8 + i, isf32);
    be1v[i] = ld(b_e1, L * 32 + quad * 8 + i, isf32);
  }

  float acc[9][4] = {};  // [c][ft]
  __syncthreads();

  #pragma unroll 1
  for (int stile = wave; stile < 32; stile += 4) {
    // ---- A fragment: he for sender m=lo, k=quad*8+i (r from gt) ----
    bf16x8 af;
    {
      float r = s.gt[stile * 16 + lo][8];
      #pragma unroll
      for (int i = 0; i < 8; ++i) {
        float x = r * we1v[i] + be1v[i];
        float he = x / (1.f + __expf(-x));
        af[i] = f2b(he);
      }
    }
    // ---- Y + indices (+ species for L0): all from LDS, zero global loads ---
    float Y1r[4][3], Y2r[4][5];
    int ir[4], sp4[4];
    bool vld[4];
    #pragma unroll
    for (int r4 = 0; r4 < 4; ++r4) {
      int idx = stile * 16 + quad * 4 + r4;
      vld[r4] = idx < NS;
      int i = idx + (idx >= j);
      if (i > 511) i = 511;
      ir[r4] = i;
      if (!HAS1) sp4[r4] = s.spl[i];
      const float* g = &s.gt[idx][0];   // broadcast within each quad
      Y1r[r4][0] = g[0]; Y1r[r4][1] = g[1]; Y1r[r4][2] = g[2];
      Y2r[r4][0] = g[3]; Y2r[r4][1] = g[4]; Y2r[r4][2] = g[5];
      Y2r[r4][3] = g[6]; Y2r[r4][4] = g[7];
    }
    // ---- per f-subtile: loads, K MFMAs, then message math ----
    #pragma unroll
    for (int ft = 0; ft < 4; ++ft) {
      int fcol = ft * 16 + lo;
      f32x4 xv[4];
      if (HAS1) {
        #pragma unroll
        for (int r4 = 0; r4 < 4; ++r4) xv[r4] = xs[ir[r4] * 64 + fcol];
      } else {
        #pragma unroll
        for (int r4 = 0; r4 < 4; ++r4) {
          f32x4 v = {s.X0l[sp4[r4] * 64 + fcol], 0.f, 0.f, 0.f};
          xv[r4] = v;
        }
      }
      f32x4 C[K];
      #pragma unroll
      for (int kp = 0; kp < K; ++kp) {
        const bf16x8 bh = *(const bf16x8*)&s.Bhi[(kp * 64 + fcol) * 40 + quad * 8];
        f32x4 c = {0.f, 0.f, 0.f, 0.f};
        C[kp] = __builtin_amdgcn_mfma_f32_16x16x32_bf16(af, bh, c, 0, 0, 0);
      }
      #pragma unroll
      for (int r4 = 0; r4 < 4; ++r4) {
        if (vld[r4]) {
          float s0 = xv[r4].x;
          float w0 = C[0][r4], w1 = C[1][r4], w2 = C[2][r4];
          if (HAS1) {
            float s1x = xv[r4].y, s1y = xv[r4].z, s1z = xv[r4].w;
            float w3 = C[3][r4], w4 = C[4][r4];
            float d1 = s1x * Y1r[r4][0] + s1y * Y1r[r4][1] + s1z * Y1r[r4][2];
            float cx = s1y * Y1r[r4][2] - s1z * Y1r[r4][1];
            float cy = s1z * Y1r[r4][0] - s1x * Y1r[r4][2];
            float cz = s1x * Y1r[r4][1] - s1y * Y1r[r4][0];
            acc[0][ft] += w0 * s0 + w3 * d1;
            float t1 = w1 * s0;
            acc[1][ft] += t1 * Y1r[r4][0] + w4 * cx;
            acc[2][ft] += t1 * Y1r[r4][1] + w4 * cy;
            acc[3][ft] += t1 * Y1r[r4][2] + w4 * cz;
          } else {
            acc[0][ft] += w0 * s0;
            float t1 = w1 * s0;
            acc[1][ft] += t1 * Y1r[r4][0];
            acc[2][ft] += t1 * Y1r[r4][1];
            acc[3][ft] += t1 * Y1r[r4][2];
          }
          float t2 = w2 * s0;
          acc[4][ft] += t2 * Y2r[r4][0];
          acc[5][ft] += t2 * Y2r[r4][1];
          acc[6][ft] += t2 * Y2r[r4][2];
          acc[7][ft] += t2 * Y2r[r4][3];
          acc[8][ft] += t2 * Y2r[r4][4];
        }
      }
    }
  }

  // ---- reduce over quads (butterfly), then over 4 waves (LDS) -> Af ----
  #pragma unroll
  for (int c = 0; c < 9; ++c)
    #pragma unroll
    for (int ft = 0; ft < 4; ++ft) {
      float v = acc[c][ft];
      v += __shfl_xor(v, 16);
      v += __shfl_xor(v, 32);
      acc[c][ft] = v;
    }
  if (quad == 0) {
    #pragma unroll
    for (int c = 0; c < 9; ++c)
      #pragma unroll
      for (int ft = 0; ft < 4; ++ft)
        s.red[wave][ft * 16 + lo][c] = acc[c][ft];
  }
  __syncthreads();
  for (int o = t; o < 576; o += 256) {
    int f = o / 9, c = o % 9;
    s.Af[f][c] = (s.red[0][f][c] + s.red[1][f][c] + s.red[2][f][c] +
                  s.red[3][f][c]) * (1.f / 511.f);
  }
  __syncthreads();

  // ---- node-update tail (wave 0; other waves ride the barriers) ----
  float out0 = 0.f, o1x = 0.f, o1y = 0.f, o1z = 0.f;
  if (t < 64) {
    int f = t;
    float a[9];
    #pragma unroll
    for (int c = 0; c < 9; ++c) a[c] = s.Af[f][c];
    int sp = nodef[j] - 1;
    int b0i = ((L * 5 + sp) * 64 + f) * 6;
    int b1i = ((L * 5 + sp) * 64 + f) * 3;
    float A0 = a[0];
    float n1 = a[1] * a[1] + a[2] * a[2] + a[3] * a[3];
    float n2 = a[4] * a[4] + a[5] * a[5] + a[6] * a[6] + a[7] * a[7] + a[8] * a[8];
    float A02 = A0 * A0;
    out0 = ld(Wp0, b0i + 0, isf32) * A0 + ld(Wp0, b0i + 1, isf32) * A02 +
           ld(Wp0, b0i + 2, isf32) * A02 * A0 + ld(Wp0, b0i + 3, isf32) * n1 +
           ld(Wp0, b0i + 4, isf32) * n2 + ld(Wp0, b0i + 5, isf32) * A0 * n1;
    float gp = ld(Wp1, b1i + 0, isf32) + ld(Wp1, b1i + 1, isf32) * A0 +
               ld(Wp1, b1i + 2, isf32) * A02;
    o1x = gp * a[1]; o1y = gp * a[2]; o1z = gp * a[3];
    s.s0l[f] = out0;
    if (L == 0) { s.o1l[0][f] = o1x; s.o1l[1][f] = o1y; s.o1l[2][f] = o1z; }
  }
  __syncthreads();
  if (t < 64) {
    int f = t;
    if (L == 0) {
      // next-layer node linear into XS1 (read in the next dispatch)
      float b0 = 0.f, bx = 0.f, by = 0.f, bz = 0.f;
      #pragma unroll 8
      for (int q = 0; q < 64; ++q) {
        float w0 = ld(W_lin, 3 * 4096 + q * 64 + f, isf32);  // layer1, path0
        float w1 = ld(W_lin, 4 * 4096 + q * 64 + f, isf32);  // layer1, path1
        b0 += s.s0l[q] * w0;
        bx += s.o1l[0][q] * w1; by += s.o1l[1][q] * w1; bz += s.o1l[2][q] * w1;
      }
      f32x4 o = {b0, bx, by, bz};
      *(f32x4*)&ws[WS_XS1 + (j * 64 + f) * 4] = o;
    }
    float hacc = ld(br1, L * 64 + f, isf32);
    #pragma unroll 8
    for (int q = 0; q < 64; ++q)
      hacc += s.s0l[q] * ld(Wr1, (L * 64 + q) * 64 + f, isf32);
    s.hl[f] = hacc / (1.f + __expf(-hacc));
  }
  __syncthreads();
  if (t < 64) {
    int f = t;
    float gacc = 0.f;
    #pragma unroll 8
    for (int m = 0; m < 64; ++m)
      gacc += s.hl[m] * ld(Wr2g, (L * 64 + m) * 64 + f, isf32);
    float px = gacc * o1x, py = gacc * o1y, pz = gacc * o1z;
    #pragma unroll
    for (int off = 32; off > 0; off >>= 1) {
      px += __shfl_down(px, off);
      py += __shfl_down(py, off);
      pz += __shfl_down(pz, off);
    }
    if (f == 0) {
      if (L == 0) {
        ws[WS_DELTA + j * 3 + 0] = px;
        ws[WS_DELTA + j * 3 + 1] = py;
        ws[WS_DELTA + j * 3 + 2] = pz;
        ws[WS_POS2 + j * 3 + 0] = pos[j * 3 + 0] + px;
        ws[WS_POS2 + j * 3 + 1] = pos[j * 3 + 1] + py;
        ws[WS_POS2 + j * 3 + 2] = pos[j * 3 + 2] + pz;
      } else {
        float ox = ws[WS_DELTA + j * 3 + 0] + px;
        float oy = ws[WS_DELTA + j * 3 + 1] + py;
        float oz = ws[WS_DELTA + j * 3 + 2] + pz;
        if (isf32) {
          float* o = (float*)out;
          o[j * 3 + 0] = ox; o[j * 3 + 1] = oy; o[j * 3 + 2] = oz;
        } else {
          bf16* o = (bf16*)out;
          o[j * 3 + 0] = __float2bfloat16(ox);
          o[j * 3 + 1] = __float2bfloat16(oy);
          o[j * 3 + 2] = __float2bfloat16(oz);
        }
      }
    }
  }
}

// ---------------- standalone kernels (the executed path) ----------------
__global__ __launch_bounds__(256) void k_pre(
    const void* __restrict__ positions, const void* __restrict__ te,
    const void* __restrict__ W_embed, const void* __restrict__ b_embed,
    const void* __restrict__ W_lin, float* __restrict__ ws) {
  __shared__ float scr[576];
  __shared__ int flag;
  pre_body(blockIdx.x, threadIdx.x, scr, &flag, positions, te, W_embed,
           b_embed, W_lin, ws);
}

template <int L>
__global__ __launch_bounds__(256) void k_edgenode(
    const int* __restrict__ nodef, const void* __restrict__ W_lin,
    const void* __restrict__ W_e1, const void* __restrict__ b_e1,
    const void* __restrict__ W_e2, const void* __restrict__ Wp0,
    const void* __restrict__ Wp1, const void* __restrict__ Wr1,
    const void* __restrict__ br1, const void* __restrict__ Wr2g,
    float* __restrict__ ws, void* __restrict__ out) {
  __shared__ SB s;
  edge_body<L>(blockIdx.x, threadIdx.x, s, nodef, W_lin, W_e1, b_e1, W_e2,
               Wp0, Wp1, Wr1, br1, Wr2g, ws, out);
}

// ---------------- fused cooperative kernel: KEPT IN MODULE, NEVER LAUNCHED --
// Compilation anchor only (rounds 3/4 proved coop launch can't run under
// graph capture; keeping the symbol preserves the favorable codegen context).
__global__ __launch_bounds__(256) void k_fused(
    const void* positions, const int* nodef, const void* te,
    const void* W_embed, const void* b_embed, const void* W_lin,
    const void* W_e1, const void* b_e1, const void* W_e2,
    const void* Wp0, const void* Wp1, const void* Wr1, const void* br1,
    const void* Wr2g, float* ws, void* out) {
  __shared__ SB s;
  cg::grid_group g = cg::this_grid();
  if (blockIdx.x < 6)
    pre_body(blockIdx.x, threadIdx.x, &s.red[0][0][0], &s.flag,
             positions, te, W_embed, b_embed, W_lin, ws);
  g.sync();
  edge_body<0>(blockIdx.x, threadIdx.x, s, nodef, W_lin, W_e1, b_e1, W_e2,
               Wp0, Wp1, Wr1, br1, Wr2g, ws, out);
  g.sync();
  edge_body<1>(blockIdx.x, threadIdx.x, s, nodef, W_lin, W_e1, b_e1, W_e2,
               Wp0, Wp1, Wr1, br1, Wr2g, ws, out);
}

extern "C" void kernel_launch(void* const* d_in, const int* in_sizes, int n_in,
                              void* d_out, int out_size, void* d_ws, size_t ws_size,
                              hipStream_t stream) {
  const void* positions = d_in[0];
  const int*  nodef     = (const int*)d_in[1];
  const void* te        = d_in[2];
  const void* W_embed   = d_in[5];
  const void* b_embed   = d_in[6];
  const void* W_lin     = d_in[7];
  const void* W_e1      = d_in[8];
  const void* b_e1      = d_in[9];
  const void* W_e2      = d_in[10];
  const void* Wp0       = d_in[11];
  const void* Wp1       = d_in[12];
  const void* Wr1       = d_in[13];
  const void* br1       = d_in[14];
  const void* Wr2g      = d_in[16];
  float* ws = (float*)d_ws;
  (void)in_sizes; (void)n_in; (void)out_size; (void)ws_size;

  k_pre<<<dim3(6), dim3(256), 0, stream>>>(positions, te, W_embed, b_embed,
                                           W_lin, ws);
  k_edgenode<0><<<dim3(512), dim3(256), 0, stream>>>(
      nodef, W_lin, W_e1, b_e1, W_e2, Wp0, Wp1, Wr1, br1, Wr2g, ws, d_out);
  k_edgenode<1><<<dim3(512), dim3(256), 0, stream>>>(
      nodef, W_lin, W_e1, b_e1, W_e2, Wp0, Wp1, Wr1, br1, Wr2g, ws, d_out);
}

// Round 10
// 180.473 us; speedup vs baseline: 1.1312x; 1.0006x over previous
//
#include <hip/hip_runtime.h>
#include <hip/hip_bf16.h>
#include <hip/hip_cooperative_groups.h>

namespace cg = cooperative_groups;

using bf16 = __hip_bfloat16;
using bf16x8 = __attribute__((ext_vector_type(8))) short;  // 8 bf16 (4 VGPRs)
using f32x4  = __attribute__((ext_vector_type(4))) float;

#define NN 512
#define NS 511

// ---------------- workspace layout (float offsets) ----------------
enum : int {
  WS_FLAG = 0,        // int: 0 = bf16 inputs, 1 = f32 inputs
  WS_X0S  = 16,       // [5][64] species-indexed layer-0 x0 rows (only 5 distinct!)
  WS_POS  = 336,      // [512][3] positions fp32 (layer 0)
  WS_POS2 = 1872,     // [512][3] positions after layer-0 update (layer 1 reads)
  WS_DELTA= 3408,     // [512][3] layer-0 displacement
  WS_XS1  = 4960,     // [512][64][4] (x0,x1x,x1y,x1z) for layer 1 — 16B aligned
};                     // end = 136032 floats ~= 544 KB

// ============================ SESSION FLOOR NOTE =============================
// This module is the twice-verified best (R5: 179.2 us, R8: 180.6 us; noise
// +-6 us). R9 bench was an infra failure (container), no kernel signal.
// Per-dispatch floor 58.6-60.7 us at VGPR_Count=128, 2 waves/SIMD.
// Constraints that define the floor (do not re-attempt without new tools):
//  * Unified VGPR+AGPR wave footprint ~224 regs pins 2 waves/SIMD; 4 of 5
//    loop edits this session tripped 128->136 VGPR => 1 wave/SIMD, +35%.
//  * Loop is latency-bound (VALUBusy 39%, MfmaUtil 3.4%, HBM 0.6%) — no pipe
//    near saturation; gains require +residency, blocked above.
//  * ~57 us of dur_us is fixed harness reset/graph overhead, insensitive to
//    launch count (R0/R5/R6: 3,3,2 launches -> same gap).
//  * Remaining micro-levers (X0l bank pad, float4 gt reads, tail wave-split,
//    L0/L1 spin-barrier merge) each < noise and re-roll the regalloc lottery.
// =============================================================================

// exact RNE float->bf16 bits (no NaN inputs here)
__device__ __forceinline__ short f2b(float x) {
  unsigned u = __builtin_bit_cast(unsigned, x);
  unsigned r = (u + 0x7fffu + ((u >> 16) & 1u)) >> 16;
  return (short)r;
}

// dtype-branched scalar load (branch, NOT select: f32-view OOB if input is bf16)
__device__ __forceinline__ float ld(const void* p, int i, int isf32) {
  if (isf32) return ((const float*)p)[i];
  return __bfloat162float(((const bf16*)p)[i]);
}

// Shared block for the edgenode body (sized for L=1; L=0 uses a prefix of Bhi)
// gt: per-edge-slot geometry (Y1[3], Y2[5], r, pad) computed once at staging —
// removes all in-loop pos loads + Y/sqrt recompute from the 8x-replicated
// stile loop. Row stride 10 floats: lane-strided reads hit 16 distinct banks.
struct SB {
  short Bhi[320 * 40];   // [n][h], row stride 40 shorts (80B, 16B-aligned)
  float red[4][64][9];
  float Af[64][9];
  float s0l[64];
  float o1l[3][64];
  float hl[64];
  float X0l[320];        // L0: species-indexed x0 table
  float gt[NN][10];      // per-edge-slot geometry table (j-specific)
  int   spl[NN];         // L0: species per node
  int   flag;
};

// ---------------- pre body (dtype sniff + pos convert + X0S) ----------------
// b<5: X0S[b]; b==5: flag + pos convert. scr: >=576 floats of scratch.
__device__ __forceinline__ void pre_body(
    int b, int t, float* scr, int* flagp,
    const void* positions, const void* te, const void* W_embed,
    const void* b_embed, const void* W_lin, float* ws) {
  float* tvp = scr;          // [4][64]
  float* hst = scr + 256;    // [64]
  float* xp  = scr + 320;    // [4][64]
  if (t < 64) {
    int cnt = 0;
    #pragma unroll
    for (int kq = 0; kq < 4; ++kq) {
      float v = __bfloat162float(((const bf16*)W_embed)[t + kq * 64]);
      float av = fabsf(v);
      cnt += (v == v && av > 1e-8f && av < 1e4f) ? 1 : 0;
    }
    #pragma unroll
    for (int off = 32; off > 0; off >>= 1) cnt += __shfl_down(cnt, off);
    if (t == 0) *flagp = (cnt >= 240) ? 0 : 1;
  }
  __syncthreads();
  const int isf32 = *flagp;

  if (b == 5) {
    if (t == 0) ((int*)ws)[WS_FLAG] = isf32;
    for (int idx = t; idx < NN * 3; idx += 256)
      ws[WS_POS + idx] = ld(positions, idx, isf32);
  } else {
    {
      int q = t & 63, kc = t >> 6;  // 4 k-chunks of 8
      float ptv = 0.f;
      #pragma unroll
      for (int k = kc * 8; k < kc * 8 + 8; ++k)
        ptv += ld(te, k, isf32) * ld(W_embed, (5 + k) * 64 + q, isf32);
      tvp[kc * 64 + q] = ptv;
    }
    __syncthreads();
    if (t < 64)
      hst[t] = tvp[t] + tvp[64 + t] + tvp[128 + t] + tvp[192 + t] +
               ld(b_embed, t, isf32) + ld(W_embed, b * 64 + t, isf32);
    __syncthreads();
    {
      int f = t & 63, qc = t >> 6;  // 4 q-chunks of 16
      float px = 0.f;
      #pragma unroll
      for (int q2 = qc * 16; q2 < qc * 16 + 16; ++q2)
        px += hst[q2] * ld(W_lin, q2 * 64 + f, isf32);  // layer0 path0
      xp[qc * 64 + f] = px;
    }
    __syncthreads();
    if (t < 64)
      ws[WS_X0S + b * 64 + t] = xp[t] + xp[64 + t] + xp[128 + t] + xp[192 + t];
  }
}

// ---------------- fused edge + aggregate + node update --------------
// 59.4 us/dispatch verified loop (128 VGPR, 2 waves/SIMD). Do not add live
// state to the stile loop (see SESSION FLOOR NOTE).
template <int L>
__device__ __forceinline__ void edge_body(
    int j, int t, SB& s,
    const int* __restrict__ nodef, const void* __restrict__ W_lin,
    const void* __restrict__ W_e1, const void* __restrict__ b_e1,
    const void* __restrict__ W_e2, const void* __restrict__ Wp0,
    const void* __restrict__ Wp1, const void* __restrict__ Wr1,
    const void* __restrict__ br1, const void* __restrict__ Wr2g,
    float* __restrict__ ws, void* __restrict__ out) {
  constexpr int HAS1 = L;          // s1==0 in layer 0
  constexpr int K = HAS1 ? 5 : 3;  // s2==0 always
  constexpr int N = K * 64;
  const int lane = t & 63;
  const int wave = t >> 6;          // 0..3
  const int quad = lane >> 4;
  const int lo = lane & 15;

  const int isf32 = ((const int*)ws)[WS_FLAG];
  const float* pos = ws + (L ? WS_POS2 : WS_POS);

  const float s3 = 1.7320508075688772f;
  const float s5h = 1.118033988749895f;    // 0.5*sqrt(5)
  const float s15 = 3.872983346207417f;
  const float s15h = 1.9364916731037085f;  // 0.5*sqrt(15)

  const float pjx = pos[j * 3 + 0], pjy = pos[j * 3 + 1], pjz = pos[j * 3 + 2];

  {  // stage W2 slice -> LDS bf16 (direct bit copy if input already bf16)
    for (int idx = t; idx < N * 32; idx += 256) {
      int n = idx >> 5, h = idx & 31;
      int kp = n >> 6, f = n & 63;
      int src = (L * 32 + h) * 384 + f * 6 + kp;
      short bits;
      if (isf32) bits = f2b(((const float*)W_e2)[src]);
      else       bits = ((const short*)W_e2)[src];
      s.Bhi[n * 40 + h] = bits;
    }
    if (!HAS1) {
      for (int idx = t; idx < 320; idx += 256) s.X0l[idx] = ws[WS_X0S + idx];
      for (int idx = t; idx < NN; idx += 256) s.spl[idx] = nodef[idx] - 1;
    }
    // geometry table: gt[ida] = {Y1(3), Y2(5), r} for edge slot ida -> j
    for (int ida = t; ida < NN; ida += 256) {
      int ia = ida + (ida >= j);
      if (ia > 511) ia = 511;
      float vx = pjx - pos[ia * 3 + 0];
      float vy = pjy - pos[ia * 3 + 1];
      float vz = pjz - pos[ia * 3 + 2];
      float r2 = vx * vx + vy * vy + vz * vz;
      float r = sqrtf(r2);
      float rinv = r2 > 0.f ? rsqrtf(r2) : 0.f;
      float ux = vx * rinv, uy = vy * rinv, uz = vz * rinv;
      float* g = &s.gt[ida][0];
      g[0] = s3 * ux; g[1] = s3 * uy; g[2] = s3 * uz;
      g[3] = s15 * ux * uy;
      g[4] = s15 * uy * uz;
      g[5] = s5h * (3.f * uz * uz - 1.f);
      g[6] = s15 * ux * uz;
      g[7] = s15h * (ux * ux - uy * uy);
      g[8] = r;
    }
  }
  const f32x4* xs = (const f32x4*)(ws + WS_XS1);  // used only for L==1
  float we1v[8], be1v[8];
  #pragma unroll
  for (int i = 0; i < 8; ++i) {
    we1v[i] = ld(W_e1, L * 32 + quad * 8 + i, isf32);
    be1v[i] = ld(b_e1, L * 32 + quad * 8 + i, isf32);
  }

  float acc[9][4] = {};  // [c][ft]
  __syncthreads();

  #pragma unroll 1
  for (int stile = wave; stile < 32; stile += 4) {
    // ---- A fragment: he for sender m=lo, k=quad*8+i (r from gt) ----
    bf16x8 af;
    {
      float r = s.gt[stile * 16 + lo][8];
      #pragma unroll
      for (int i = 0; i < 8; ++i) {
        float x = r * we1v[i] + be1v[i];
        float he = x / (1.f + __expf(-x));
        af[i] = f2b(he);
      }
    }
    // ---- Y + indices (+ species for L0): all from LDS, zero global loads ---
    float Y1r[4][3], Y2r[4][5];
    int ir[4], sp4[4];
    bool vld[4];
    #pragma unroll
    for (int r4 = 0; r4 < 4; ++r4) {
      int idx = stile * 16 + quad * 4 + r4;
      vld[r4] = idx < NS;
      int i = idx + (idx >= j);
      if (i > 511) i = 511;
      ir[r4] = i;
      if (!HAS1) sp4[r4] = s.spl[i];
      const float* g = &s.gt[idx][0];   // broadcast within each quad
      Y1r[r4][0] = g[0]; Y1r[r4][1] = g[1]; Y1r[r4][2] = g[2];
      Y2r[r4][0] = g[3]; Y2r[r4][1] = g[4]; Y2r[r4][2] = g[5];
      Y2r[r4][3] = g[6]; Y2r[r4][4] = g[7];
    }
    // ---- per f-subtile: loads, K MFMAs, then message math ----
    #pragma unroll
    for (int ft = 0; ft < 4; ++ft) {
      int fcol = ft * 16 + lo;
      f32x4 xv[4];
      if (HAS1) {
        #pragma unroll
        for (int r4 = 0; r4 < 4; ++r4) xv[r4] = xs[ir[r4] * 64 + fcol];
      } else {
        #pragma unroll
        for (int r4 = 0; r4 < 4; ++r4) {
          f32x4 v = {s.X0l[sp4[r4] * 64 + fcol], 0.f, 0.f, 0.f};
          xv[r4] = v;
        }
      }
      f32x4 C[K];
      #pragma unroll
      for (int kp = 0; kp < K; ++kp) {
        const bf16x8 bh = *(const bf16x8*)&s.Bhi[(kp * 64 + fcol) * 40 + quad * 8];
        f32x4 c = {0.f, 0.f, 0.f, 0.f};
        C[kp] = __builtin_amdgcn_mfma_f32_16x16x32_bf16(af, bh, c, 0, 0, 0);
      }
      #pragma unroll
      for (int r4 = 0; r4 < 4; ++r4) {
        if (vld[r4]) {
          float s0 = xv[r4].x;
          float w0 = C[0][r4], w1 = C[1][r4], w2 = C[2][r4];
          if (HAS1) {
            float s1x = xv[r4].y, s1y = xv[r4].z, s1z = xv[r4].w;
            float w3 = C[3][r4], w4 = C[4][r4];
            float d1 = s1x * Y1r[r4][0] + s1y * Y1r[r4][1] + s1z * Y1r[r4][2];
            float cx = s1y * Y1r[r4][2] - s1z * Y1r[r4][1];
            float cy = s1z * Y1r[r4][0] - s1x * Y1r[r4][2];
            float cz = s1x * Y1r[r4][1] - s1y * Y1r[r4][0];
            acc[0][ft] += w0 * s0 + w3 * d1;
            float t1 = w1 * s0;
            acc[1][ft] += t1 * Y1r[r4][0] + w4 * cx;
            acc[2][ft] += t1 * Y1r[r4][1] + w4 * cy;
            acc[3][ft] += t1 * Y1r[r4][2] + w4 * cz;
          } else {
            acc[0][ft] += w0 * s0;
            float t1 = w1 * s0;
            acc[1][ft] += t1 * Y1r[r4][0];
            acc[2][ft] += t1 * Y1r[r4][1];
            acc[3][ft] += t1 * Y1r[r4][2];
          }
          float t2 = w2 * s0;
          acc[4][ft] += t2 * Y2r[r4][0];
          acc[5][ft] += t2 * Y2r[r4][1];
          acc[6][ft] += t2 * Y2r[r4][2];
          acc[7][ft] += t2 * Y2r[r4][3];
          acc[8][ft] += t2 * Y2r[r4][4];
        }
      }
    }
  }

  // ---- reduce over quads (butterfly), then over 4 waves (LDS) -> Af ----
  #pragma unroll
  for (int c = 0; c < 9; ++c)
    #pragma unroll
    for (int ft = 0; ft < 4; ++ft) {
      float v = acc[c][ft];
      v += __shfl_xor(v, 16);
      v += __shfl_xor(v, 32);
      acc[c][ft] = v;
    }
  if (quad == 0) {
    #pragma unroll
    for (int c = 0; c < 9; ++c)
      #pragma unroll
      for (int ft = 0; ft < 4; ++ft)
        s.red[wave][ft * 16 + lo][c] = acc[c][ft];
  }
  __syncthreads();
  for (int o = t; o < 576; o += 256) {
    int f = o / 9, c = o % 9;
    s.Af[f][c] = (s.red[0][f][c] + s.red[1][f][c] + s.red[2][f][c] +
                  s.red[3][f][c]) * (1.f / 511.f);
  }
  __syncthreads();

  // ---- node-update tail (wave 0; other waves ride the barriers) ----
  float out0 = 0.f, o1x = 0.f, o1y = 0.f, o1z = 0.f;
  if (t < 64) {
    int f = t;
    float a[9];
    #pragma unroll
    for (int c = 0; c < 9; ++c) a[c] = s.Af[f][c];
    int sp = nodef[j] - 1;
    int b0i = ((L * 5 + sp) * 64 + f) * 6;
    int b1i = ((L * 5 + sp) * 64 + f) * 3;
    float A0 = a[0];
    float n1 = a[1] * a[1] + a[2] * a[2] + a[3] * a[3];
    float n2 = a[4] * a[4] + a[5] * a[5] + a[6] * a[6] + a[7] * a[7] + a[8] * a[8];
    float A02 = A0 * A0;
    out0 = ld(Wp0, b0i + 0, isf32) * A0 + ld(Wp0, b0i + 1, isf32) * A02 +
           ld(Wp0, b0i + 2, isf32) * A02 * A0 + ld(Wp0, b0i + 3, isf32) * n1 +
           ld(Wp0, b0i + 4, isf32) * n2 + ld(Wp0, b0i + 5, isf32) * A0 * n1;
    float gp = ld(Wp1, b1i + 0, isf32) + ld(Wp1, b1i + 1, isf32) * A0 +
               ld(Wp1, b1i + 2, isf32) * A02;
    o1x = gp * a[1]; o1y = gp * a[2]; o1z = gp * a[3];
    s.s0l[f] = out0;
    if (L == 0) { s.o1l[0][f] = o1x; s.o1l[1][f] = o1y; s.o1l[2][f] = o1z; }
  }
  __syncthreads();
  if (t < 64) {
    int f = t;
    if (L == 0) {
      // next-layer node linear into XS1 (read in the next dispatch)
      float b0 = 0.f, bx = 0.f, by = 0.f, bz = 0.f;
      #pragma unroll 8
      for (int q = 0; q < 64; ++q) {
        float w0 = ld(W_lin, 3 * 4096 + q * 64 + f, isf32);  // layer1, path0
        float w1 = ld(W_lin, 4 * 4096 + q * 64 + f, isf32);  // layer1, path1
        b0 += s.s0l[q] * w0;
        bx += s.o1l[0][q] * w1; by += s.o1l[1][q] * w1; bz += s.o1l[2][q] * w1;
      }
      f32x4 o = {b0, bx, by, bz};
      *(f32x4*)&ws[WS_XS1 + (j * 64 + f) * 4] = o;
    }
    float hacc = ld(br1, L * 64 + f, isf32);
    #pragma unroll 8
    for (int q = 0; q < 64; ++q)
      hacc += s.s0l[q] * ld(Wr1, (L * 64 + q) * 64 + f, isf32);
    s.hl[f] = hacc / (1.f + __expf(-hacc));
  }
  __syncthreads();
  if (t < 64) {
    int f = t;
    float gacc = 0.f;
    #pragma unroll 8
    for (int m = 0; m < 64; ++m)
      gacc += s.hl[m] * ld(Wr2g, (L * 64 + m) * 64 + f, isf32);
    float px = gacc * o1x, py = gacc * o1y, pz = gacc * o1z;
    #pragma unroll
    for (int off = 32; off > 0; off >>= 1) {
      px += __shfl_down(px, off);
      py += __shfl_down(py, off);
      pz += __shfl_down(pz, off);
    }
    if (f == 0) {
      if (L == 0) {
        ws[WS_DELTA + j * 3 + 0] = px;
        ws[WS_DELTA + j * 3 + 1] = py;
        ws[WS_DELTA + j * 3 + 2] = pz;
        ws[WS_POS2 + j * 3 + 0] = pos[j * 3 + 0] + px;
        ws[WS_POS2 + j * 3 + 1] = pos[j * 3 + 1] + py;
        ws[WS_POS2 + j * 3 + 2] = pos[j * 3 + 2] + pz;
      } else {
        float ox = ws[WS_DELTA + j * 3 + 0] + px;
        float oy = ws[WS_DELTA + j * 3 + 1] + py;
        float oz = ws[WS_DELTA + j * 3 + 2] + pz;
        if (isf32) {
          float* o = (float*)out;
          o[j * 3 + 0] = ox; o[j * 3 + 1] = oy; o[j * 3 + 2] = oz;
        } else {
          bf16* o = (bf16*)out;
          o[j * 3 + 0] = __float2bfloat16(ox);
          o[j * 3 + 1] = __float2bfloat16(oy);
          o[j * 3 + 2] = __float2bfloat16(oz);
        }
      }
    }
  }
}

// ---------------- standalone kernels (the executed path) ----------------
__global__ __launch_bounds__(256) void k_pre(
    const void* __restrict__ positions, const void* __restrict__ te,
    const void* __restrict__ W_embed, const void* __restrict__ b_embed,
    const void* __restrict__ W_lin, float* __restrict__ ws) {
  __shared__ float scr[576];
  __shared__ int flag;
  pre_body(blockIdx.x, threadIdx.x, scr, &flag, positions, te, W_embed,
           b_embed, W_lin, ws);
}

template <int L>
__global__ __launch_bounds__(256) void k_edgenode(
    const int* __restrict__ nodef, const void* __restrict__ W_lin,
    const void* __restrict__ W_e1, const void* __restrict__ b_e1,
    const void* __restrict__ W_e2, const void* __restrict__ Wp0,
    const void* __restrict__ Wp1, const void* __restrict__ Wr1,
    const void* __restrict__ br1, const void* __restrict__ Wr2g,
    float* __restrict__ ws, void* __restrict__ out) {
  __shared__ SB s;
  edge_body<L>(blockIdx.x, threadIdx.x, s, nodef, W_lin, W_e1, b_e1, W_e2,
               Wp0, Wp1, Wr1, br1, Wr2g, ws, out);
}

// ---------------- fused cooperative kernel: KEPT IN MODULE, NEVER LAUNCHED --
// Compilation anchor only (rounds 3/4 proved coop launch can't run under
// graph capture; keeping the symbol preserves the favorable codegen context).
__global__ __launch_bounds__(256) void k_fused(
    const void* positions, const int* nodef, const void* te,
    const void* W_embed, const void* b_embed, const void* W_lin,
    const void* W_e1, const void* b_e1, const void* W_e2,
    const void* Wp0, const void* Wp1, const void* Wr1, const void* br1,
    const void* Wr2g, float* ws, void* out) {
  __shared__ SB s;
  cg::grid_group g = cg::this_grid();
  if (blockIdx.x < 6)
    pre_body(blockIdx.x, threadIdx.x, &s.red[0][0][0], &s.flag,
             positions, te, W_embed, b_embed, W_lin, ws);
  g.sync();
  edge_body<0>(blockIdx.x, threadIdx.x, s, nodef, W_lin, W_e1, b_e1, W_e2,
               Wp0, Wp1, Wr1, br1, Wr2g, ws, out);
  g.sync();
  edge_body<1>(blockIdx.x, threadIdx.x, s, nodef, W_lin, W_e1, b_e1, W_e2,
               Wp0, Wp1, Wr1, br1, Wr2g, ws, out);
}

extern "C" void kernel_launch(void* const* d_in, const int* in_sizes, int n_in,
                              void* d_out, int out_size, void* d_ws, size_t ws_size,
                              hipStream_t stream) {
  const void* positions = d_in[0];
  const int*  nodef     = (const int*)d_in[1];
  const void* te        = d_in[2];
  const void* W_embed   = d_in[5];
  const void* b_embed   = d_in[6];
  const void* W_lin     = d_in[7];
  const void* W_e1      = d_in[8];
  const void* b_e1      = d_in[9];
  const void* W_e2      = d_in[10];
  const void* Wp0       = d_in[11];
  const void* Wp1       = d_in[12];
  const void* Wr1       = d_in[13];
  const void* br1       = d_in[14];
  const void* Wr2g      = d_in[16];
  float* ws = (float*)d_ws;
  (void)in_sizes; (void)n_in; (void)out_size; (void)ws_size;

  k_pre<<<dim3(6), dim3(256), 0, stream>>>(positions, te, W_embed, b_embed,
                                           W_lin, ws);
  k_edgenode<0><<<dim3(512), dim3(256), 0, stream>>>(
      nodef, W_lin, W_e1, b_e1, W_e2, Wp0, Wp1, Wr1, br1, Wr2g, ws, d_out);
  k_edgenode<1><<<dim3(512), dim3(256), 0, stream>>>(
      nodef, W_lin, W_e1, b_e1, W_e2, Wp0, Wp1, Wr1, br1, Wr2g, ws, d_out);
}